// Round 9
// baseline (27869.031 us; speedup 1.0000x reference)
//
#include <hip/hip_runtime.h>
#include <hip/hip_bf16.h>
#include <stdint.h>

#define AG __HIP_MEMORY_SCOPE_AGENT
typedef unsigned long long ull;

// ---------------- workspace layout (bytes) ----------------
static constexpr size_t OFF_WA  = 0;                 // [2][256][256][9] uint4 (att-LSTM regs)
static constexpr size_t OFF_W1  = 18874368;          // [2][256][16][2184] bf16
static constexpr size_t OFF_W2  = 54657024;          // [2][256][16][2056] bf16
static constexpr size_t OFF_WD  = 88342528;          // [2][256][256][2] uint4
static constexpr size_t OFF_WO  = 92536832;          // [2][80][256][2] uint2
static constexpr size_t OFF_WQ  = 93192192;          // [2][192][256] uint2
static constexpr size_t OFF_VL  = 93978624;          // [2][192][16] uint4 (vals s-major)
static constexpr size_t OFF_KEY = 94109696;          // [2][192][128] f32
static constexpr size_t OFF_V32 = 94306304;          // [2][192][128] f32 vals
static constexpr size_t OFF_WQT = 94502912;          // [2][128][1024] f32 Wq^T
static constexpr size_t OFF_ENC = 95551488;          // [192][640] f32
static constexpr size_t OFF_RB  = 96043008;          // residual^T [512][80] f32
static constexpr size_t OFF_SEQ = 96206848;          // intermediate seq [512][80] f32
static constexpr size_t OFF_DYN = 96370688;
static constexpr size_t OFF_HAb = OFF_DYN + 0;       // ha [1024] f32 (tagged)
static constexpr size_t OFF_H1b = OFF_DYN + 4096;    // h1 [1024] (tagged)
static constexpr size_t OFF_H2b = OFF_DYN + 8192;    // h2 [1024] (tagged)
static constexpr size_t OFF_HDb = OFF_DYN + 12288;   // hd [1024] (tagged)
static constexpr size_t OFF_BPL = OFF_DYN + 16384;   // bp[80] | ls[80] (tagged), 256 alloc
static constexpr size_t OFF_SCb = OFF_DYN + 17408;   // scores, stride 4 (768 floats)
static constexpr size_t DYN_BYTES = 20480;
static constexpr size_t NEEDED = OFF_DYN + DYN_BYTES;

// ---------------- device helpers ----------------
__device__ __forceinline__ float aldx(const float* p){ return __hip_atomic_load(p, __ATOMIC_RELAXED, AG); }
__device__ __forceinline__ void  astx(float* p, float v){ __hip_atomic_store(p, v, __ATOMIC_RELAXED, AG); }
__device__ __forceinline__ int   PADI(int k){ return k + ((k>>5)<<2); }   // +16B per 32 floats
__device__ __forceinline__ float tagf(float f, uint32_t tag){
  return __uint_as_float((__float_as_uint(f) & ~3u) | tag);
}

__device__ __forceinline__ float dot8(uint4 w, const float* v){
  float4 a = *(const float4*)v;
  float4 b = *(const float4*)(v+4);
  float s;
  s = __uint_as_float(w.x << 16) * a.x;
  s = fmaf(__uint_as_float(w.x & 0xffff0000u), a.y, s);
  s = fmaf(__uint_as_float(w.y << 16),         a.z, s);
  s = fmaf(__uint_as_float(w.y & 0xffff0000u), a.w, s);
  s = fmaf(__uint_as_float(w.z << 16),         b.x, s);
  s = fmaf(__uint_as_float(w.z & 0xffff0000u), b.y, s);
  s = fmaf(__uint_as_float(w.w << 16),         b.z, s);
  s = fmaf(__uint_as_float(w.w & 0xffff0000u), b.w, s);
  return s;
}
__device__ __forceinline__ float dot8r(uint4 w, const float* y){  // y: 8 regs
  float s;
  s = __uint_as_float(w.x << 16) * y[0];
  s = fmaf(__uint_as_float(w.x & 0xffff0000u), y[1], s);
  s = fmaf(__uint_as_float(w.y << 16),         y[2], s);
  s = fmaf(__uint_as_float(w.y & 0xffff0000u), y[3], s);
  s = fmaf(__uint_as_float(w.z << 16),         y[4], s);
  s = fmaf(__uint_as_float(w.z & 0xffff0000u), y[5], s);
  s = fmaf(__uint_as_float(w.w << 16),         y[6], s);
  s = fmaf(__uint_as_float(w.w & 0xffff0000u), y[7], s);
  return s;
}
__device__ __forceinline__ float dot4(uint2 w, const float* v){
  float4 a = *(const float4*)v;
  float s;
  s = __uint_as_float(w.x << 16) * a.x;
  s = fmaf(__uint_as_float(w.x & 0xffff0000u), a.y, s);
  s = fmaf(__uint_as_float(w.y << 16),         a.z, s);
  s = fmaf(__uint_as_float(w.y & 0xffff0000u), a.w, s);
  return s;
}
__device__ __forceinline__ float sigf(float x){ return 1.f/(1.f+__expf(-x)); }
__device__ __forceinline__ float tanhf_(float x){
  x = fminf(12.f, fmaxf(-12.f, x));
  float t = __expf(2.f*x);
  return (t-1.f)/(t+1.f);
}

// ---------------- prep kernels ----------------
__global__ void k_init(float* z, int n){ int i = blockIdx.x*256 + threadIdx.x; if (i<n) z[i]=0.f; }

__global__ void k_rbuf(const float* res, float* rb){
  int i = blockIdx.x*256 + threadIdx.x; if (i >= 512*80) return;
  int t = i/80, m = i - t*80;
  rb[i] = res[m*512 + t];
}

__global__ void k_enc(const float* emb, const float* spk, const int* text, float* enc){
  int i = blockIdx.x*256 + threadIdx.x; if (i >= 192*640) return;
  int s = i/640, e = i - s*640;
  enc[i] = (e < 512) ? emb[(size_t)text[s]*512 + e] : spk[e-512];
}

__global__ void k_keysvals(const float* enc, const float* Wk, const float* Wv,
                           float* keys, float* vals32){
  int i = blockIdx.x*256 + threadIdx.x; if (i >= 2*192*128) return;
  int f = i/(192*128); int r = i - f*192*128; int s = r/128, a = r - s*128;
  float ka=0.f, va=0.f;
  for (int e=0;e<640;++e){
    float x = enc[s*640+e];
    ka = fmaf(x, Wk[((size_t)f*640+e)*128+a], ka);
    va = fmaf(x, Wv[((size_t)f*640+e)*128+a], va);
  }
  keys[((size_t)f*192+s)*128+a] = ka;
  vals32[((size_t)f*192+s)*128+a] = va;
}

__global__ void k_wqT(const float* Wq, float* WqT){
  int i = blockIdx.x*256 + threadIdx.x; if (i >= 2*128*1024) return;
  int f = i/(128*1024); int r = i - f*128*1024; int a = r/1024, h = r - a*1024;
  WqT[i] = Wq[((size_t)f*1024+h)*128+a];
}

__global__ void k_wqk2(const float* WqT, const float* keys, uint2* dst){
  int b = blockIdx.x; int f = b/192, s = b - f*192;
  int t = threadIdx.x;
  float4 acc = {0.f,0.f,0.f,0.f};
  const float* kp = keys + ((size_t)f*192+s)*128;
  const float* wp = WqT + (size_t)f*128*1024 + t*4;
  for (int a=0;a<128;++a){
    float kk = kp[a];
    float4 w = *(const float4*)(wp + (size_t)a*1024);
    acc.x = fmaf(kk, w.x, acc.x); acc.y = fmaf(kk, w.y, acc.y);
    acc.z = fmaf(kk, w.z, acc.z); acc.w = fmaf(kk, w.w, acc.w);
  }
  const float inv = 0.08838834764831845f;
  __hip_bfloat16 b0 = __float2bfloat16(acc.x*inv), b1 = __float2bfloat16(acc.y*inv);
  __hip_bfloat16 b2 = __float2bfloat16(acc.z*inv), b3 = __float2bfloat16(acc.w*inv);
  uint2 o;
  o.x = (uint32_t)(*(uint16_t*)&b0) | ((uint32_t)(*(uint16_t*)&b1) << 16);
  o.y = (uint32_t)(*(uint16_t*)&b2) | ((uint32_t)(*(uint16_t*)&b3) << 16);
  dst[((size_t)f*192+s)*256 + t] = o;
}

__device__ __forceinline__ uint32_t pk2(float a, float b){
  __hip_bfloat16 x = __float2bfloat16(a), y = __float2bfloat16(b);
  return (uint32_t)(*(uint16_t*)&x) | ((uint32_t)(*(uint16_t*)&y) << 16);
}

// vals packed s-major: dst[(f*192+s)*16 + ag] = 8 bf16 (a = ag*8..+8)
__global__ void k_packV2(const float* vals32, uint4* dst){
  int i = blockIdx.x*256 + threadIdx.x; if (i >= 2*192*16) return;
  int ag = i & 15; int r = i >> 4;
  int s = r % 192; int f = r / 192;
  float v[8];
  for (int e=0;e<8;++e) v[e] = vals32[((size_t)f*192+s)*128 + ag*8 + e];
  uint4 o; o.x = pk2(v[0],v[1]); o.y = pk2(v[2],v[3]); o.z = pk2(v[4],v[5]); o.w = pk2(v[6],v[7]);
  dst[i] = o;
}

__global__ void k_packA2(const float* Wih, const float* Whh, uint4* dst){
  int i = blockIdx.x*256 + threadIdx.x; if (i >= 2*256*256*9) return;
  int j = i % 9; int r = i / 9;
  int t = r & 255; r >>= 8;
  int b = r & 255; int f = r >> 8;
  int rs = t>>4, ks = t&15;
  int row = (rs>>2)*1024 + b*4 + (rs&3);
  float v[8];
  for (int e=0;e<8;++e){
    int c = ks*8 + e;
    if (j == 0) v[e] = (c < 80) ? Wih[((size_t)f*4096+row)*80 + c] : 0.f;
    else        v[e] = Whh[((size_t)f*4096+row)*1024 + (j-1)*128 + c];
  }
  uint4 o; o.x = pk2(v[0],v[1]); o.y = pk2(v[2],v[3]); o.z = pk2(v[4],v[5]); o.w = pk2(v[6],v[7]);
  dst[i] = o;
}

__global__ void k_pack1b(const float* Wih1, const float* Whh1, uint4* dst){
  int i = blockIdx.x*256 + threadIdx.x; if (i >= 2*256*16*273) return;
  int kc = i % 273; int r = i / 273;
  int rr = r & 15; r >>= 4;
  int b = r & 255; int f = r >> 8;
  int row = (rr>>2)*1024 + b*4 + (rr&3);
  int k0 = kc*8;
  float v[8];
  for (int e=0;e<8;++e){
    int k = k0+e; float x;
    if (k < 1024)      x = Wih1[((size_t)f*4096+row)*1152 + k];
    else if (k < 2048) x = Whh1[((size_t)f*4096+row)*1024 + (k-1024)];
    else if (k < 2176) x = Wih1[((size_t)f*4096+row)*1152 + 1024 + (k-2048)];
    else               x = 0.f;
    v[e] = x;
  }
  uint4 o; o.x = pk2(v[0],v[1]); o.y = pk2(v[2],v[3]); o.z = pk2(v[4],v[5]); o.w = pk2(v[6],v[7]);
  dst[i] = o;
}

__global__ void k_pack2b(const float* Wih2, const float* Whh2, uint4* dst){
  int i = blockIdx.x*256 + threadIdx.x; if (i >= 2*256*16*257) return;
  int kc = i % 257; int r = i / 257;
  int rr = r & 15; r >>= 4;
  int b = r & 255; int f = r >> 8;
  int row = (rr>>2)*1024 + b*4 + (rr&3);
  int k0 = kc*8;
  float v[8];
  for (int e=0;e<8;++e){
    int k = k0+e;
    v[e] = (k < 1024) ? Wih2[((size_t)f*4096+row)*1024 + k]
         : (k < 2048) ? Whh2[((size_t)f*4096+row)*1024 + (k-1024)] : 0.f;
  }
  uint4 o; o.x = pk2(v[0],v[1]); o.y = pk2(v[2],v[3]); o.z = pk2(v[4],v[5]); o.w = pk2(v[6],v[7]);
  dst[i] = o;
}

__global__ void k_packD2(const float* Wd, uint4* dst){
  __shared__ float tile[64][65];
  int b = blockIdx.x; int f = b >> 8; int rem = b & 255;
  int ot = rem >> 4, ct = rem & 15;
  int tid = threadIdx.x;
  for (int i = tid; i < 4096; i += 256){
    int rc = i >> 6, oc = i & 63;
    tile[rc][oc] = Wd[((size_t)f*1024 + ct*64 + rc)*1024 + ot*64 + oc];
  }
  __syncthreads();
  for (int w = 0; w < 2; ++w){
    int idx = w*256 + tid;
    int op = idx >> 3, cc = idx & 7;
    int k6 = (ct&7)*8 + cc, j = ct >> 3;
    int o = ot*64 + op;
    int b2 = o >> 2, r2 = o & 3;
    uint4 out;
    out.x = pk2(tile[cc*8+0][op], tile[cc*8+1][op]);
    out.y = pk2(tile[cc*8+2][op], tile[cc*8+3][op]);
    out.z = pk2(tile[cc*8+4][op], tile[cc*8+5][op]);
    out.w = pk2(tile[cc*8+6][op], tile[cc*8+7][op]);
    dst[((((size_t)f*256 + b2)*256) + r2*64 + k6)*2 + j] = out;
  }
}

__global__ void k_packO2(const float* Wo, uint2* dst){
  int i = blockIdx.x*256 + threadIdx.x; if (i >= 2*80*256) return;
  int t = i & 255; int r = i >> 8;
  int m = r % 80; int f = r / 80;
  for (int j = 0; j < 2; ++j){
    int row = m + j*80;
    float v[4];
    for (int e=0;e<4;++e) v[e] = Wo[((size_t)f*1024 + t*4+e)*160 + row];
    uint2 o; o.x = pk2(v[0],v[1]); o.y = pk2(v[2],v[3]);
    dst[(size_t)i*2 + j] = o;
  }
}

// ---------------- main persistent kernel (one flow) ----------------
__launch_bounds__(256, 1)
__global__ void k_flow9(uint8_t* ws, int fl, int rev, int out_mode,
    const float* b_att_all, const float* b1_all, const float* b2_all,
    const float* bd_all, const float* bo_all,
    const float* xsrc, float* ydst)
{
  const int tid = threadIdx.x, bid = blockIdx.x;
  const int rs = tid >> 4, ks = tid & 15;   // 16 rows x 16 k-slices
  const int wid = tid >> 6;
  const int ko = ks*8 + ((ks>>2)<<2);       // = PADI(ks*8)

  float* habuf = (float*)(ws + OFF_HAb);
  float* h1buf = (float*)(ws + OFF_H1b);
  float* h2buf = (float*)(ws + OFF_H2b);
  float* hdbuf = (float*)(ws + OFF_HDb);
  float* bpl   = (float*)(ws + OFF_BPL);
  float* scb   = (float*)(ws + OFF_SCb);

  __shared__ __align__(16) ushort W1s[16*2184];
  __shared__ __align__(16) ushort W2s[16*2056];
  __shared__ __align__(16) float haPrevS[1152];
  __shared__ __align__(16) float S2[1152];      // h1prev / h1
  __shared__ __align__(16) float S3[1152];      // h2prev / h2
  __shared__ __align__(16) float scratch[2048]; // ctx partials / hd staging
  __shared__ __align__(16) float ctxS[144];
  __shared__ __align__(16) float attp[288];
  __shared__ __align__(16) float bplS[184];     // PADI(159)=179 max
  __shared__ float xrow[80];
  __shared__ float zred[32];
  __shared__ float cst[3][4];
  __shared__ float bAs[16], b1s[16], b2s[16], bds[4], bos[2];

  const size_t fb = (size_t)fl*256 + bid;

  // ---- prologue: weights to LDS / regs ----
  { const uint4* src = (const uint4*)((const ushort*)(ws + OFF_W1) + fb*16*2184);
    uint4* dst = (uint4*)W1s;
    for (int i = tid; i < 4368; i += 256) dst[i] = src[i]; }
  { const uint4* src = (const uint4*)((const ushort*)(ws + OFF_W2) + fb*16*2056);
    uint4* dst = (uint4*)W2s;
    for (int i = tid; i < 4112; i += 256) dst[i] = src[i]; }
  uint4 wa[9];
  { const uint4* g = (const uint4*)(ws + OFF_WA) + (fb*256 + tid)*9;
    #pragma unroll
    for (int j = 0; j < 9; ++j) wa[j] = g[j]; }
  uint4 wd[2];
  { const uint4* g = (const uint4*)(ws + OFF_WD) + (fb*256 + tid)*2;
    wd[0] = g[0]; wd[1] = g[1]; }
  uint2 wqk = {0,0};
  if (bid < 192) wqk = ((const uint2*)(ws + OFF_WQ))[((size_t)fl*192 + bid)*256 + tid];
  uint4 vals_r[12];
  { const uint4* g = (const uint4*)(ws + OFF_VL) + (((size_t)fl*192 + rs*12)*16 + ks);
    #pragma unroll
    for (int j = 0; j < 12; ++j) vals_r[j] = g[(size_t)j*16]; }
  uint2 wo0 = {0,0}, wo1 = {0,0};
  if (bid < 80){ const uint2* g = (const uint2*)(ws + OFF_WO) + (((size_t)fl*80 + bid)*256 + tid)*2;
    wo0 = g[0]; wo1 = g[1]; }
  if (tid < 16){
    int g = tid >> 2, uu = tid & 3;
    bAs[tid] = b_att_all[fl*4096 + g*1024 + bid*4 + uu];
    b1s[tid] = b1_all  [fl*4096 + g*1024 + bid*4 + uu];
    b2s[tid] = b2_all  [fl*4096 + g*1024 + bid*4 + uu];
  }
  if (tid < 4)  bds[tid] = bd_all[fl*1024 + bid*4 + tid];
  if (tid < 2 && bid < 80) bos[tid] = bo_all[fl*160 + tid*80 + bid];
  if (tid < 12) ((float*)cst)[tid] = 0.f;
  for (int i = tid; i < 1152; i += 256){ haPrevS[i]=0.f; S2[i]=0.f; S3[i]=0.f; }
  if (tid < 184) bplS[tid] = 0.f;
  if (tid < 80)  xrow[tid] = 0.f;
  __syncthreads();

  // Gang-load tagged poll (hot): independent loads, one combined check/iter.
  auto poll4 = [&](const float* g, float* s, uint32_t tag){
    float v0,v1,v2,v3;
    for(;;){
      v0 = aldx(g+tid);     v1 = aldx(g+tid+256);
      v2 = aldx(g+tid+512); v3 = aldx(g+tid+768);
      uint32_t ok = ((__float_as_uint(v0)&3u)==tag) & ((__float_as_uint(v1)&3u)==tag)
                  & ((__float_as_uint(v2)&3u)==tag) & ((__float_as_uint(v3)&3u)==tag);
      if (ok) break;
    }
    s[PADI(tid)]     = v0;  s[PADI(tid+256)] = v1;
    s[PADI(tid+512)] = v2;  s[PADI(tid+768)] = v3;
  };
  auto poll1 = [&](const float* g, int n, float* s, uint32_t tag){
    if (tid < n){
      float f;
      for(;;){ f = aldx(g+tid); if((__float_as_uint(f)&3u)==tag) break; }
      s[PADI(tid)] = f;
    }
  };

  const uint4* w1row = (const uint4*)(W1s) + (size_t)rs*273;
  const uint4* w2row = (const uint4*)(W2s) + (size_t)rs*257;

  float accA = 0.f;   // Whh_att @ haPrev, precomputed in hop shadow

  for (int t = 0; t < 512; ++t) {
    const int col = rev ? (511 - t) : t;
    const uint32_t TAG = (uint32_t)((t+1) & 3);

    // ===== phase A tail: reconstruct y(t-1) in-reg from bplS+xrow; gates =====
    {
      float yv[8];
      #pragma unroll
      for (int e = 0; e < 8; ++e){
        int k = ks*8 + e;
        yv[e] = (k < 80) ? (xrow[k] - bplS[PADI(k)]) * __expf(-bplS[PADI(80+k)]) : 0.f;
      }
      float acc = accA + dot8r(wa[0], yv);
      acc += __shfl_xor(acc,1); acc += __shfl_xor(acc,2);
      acc += __shfl_xor(acc,4); acc += __shfl_xor(acc,8);
      if (ks == 0) zred[rs] = acc + bAs[rs];
    }
    __syncthreads();
    if (tid < 4) {
      float zi=zred[tid], zf=zred[4+tid], zg=zred[8+tid], zo=zred[12+tid];
      float c = sigf(zf)*cst[0][tid] + sigf(zi)*tanhf_(zg);
      float h = sigf(zo)*tanhf_(c);
      cst[0][tid] = c;
      astx(habuf + bid*4 + tid, tagf(h, TAG));
    }

    // ---- hop shadow: prev-state halves of LSTM1/LSTM2 ----
    float acc1 = 0.f, acc2 = 0.f;
    #pragma unroll
    for (int j = 0; j < 8; ++j) acc1 += dot8(w1row[(j+8)*16 + ks], S2 + j*144 + ko);
    #pragma unroll
    for (int j = 0; j < 8; ++j) acc2 += dot8(w2row[(j+8)*16 + ks], S3 + j*144 + ko);

    // ---- poll ha -> haPrevS ----
    poll4(habuf, haPrevS, TAG);
    __syncthreads();

    // ===== scores (blocks 0..191): line-spread store =====
    if (bid < 192) {
      float sv = dot4(wqk, haPrevS + tid*4 + ((tid>>3)<<2));
      #pragma unroll
      for (int d=1; d<64; d<<=1) sv += __shfl_xor(sv, d);
      if (tid == 0){
        // lane 0 of wave 0 has the wave-0 sum; need all 4 wave sums
      }
      if ((tid&63) == 0) zred[16+wid] = sv;
      __syncthreads();
      if (tid == 0) astx(scb + bid*4, tagf(zred[16]+zred[17]+zred[18]+zred[19], TAG));
    }

    // ---- hop shadow: LSTM1 ha-half ----
    #pragma unroll
    for (int j = 0; j < 8; ++j) acc1 += dot8(w1row[j*16 + ks], haPrevS + j*144 + ko);

    // ===== wave-0 fused score-poll + softmax (pure shuffles, 1 barrier) =====
    if (tid < 64){
      float f0,f1,f2;
      for(;;){
        f0 = aldx(scb + tid*4); f1 = aldx(scb + (tid+64)*4); f2 = aldx(scb + (tid+128)*4);
        uint32_t ok = ((__float_as_uint(f0)&3u)==TAG) & ((__float_as_uint(f1)&3u)==TAG)
                    & ((__float_as_uint(f2)&3u)==TAG);
        if (ok) break;
      }
      float m = fmaxf(f0, fmaxf(f1, f2));
      #pragma unroll
      for (int d=1; d<64; d<<=1) m = fmaxf(m, __shfl_xor(m, d));
      float e0 = __expf(f0 - m), e1 = __expf(f1 - m), e2 = __expf(f2 - m);
      float sm = e0 + e1 + e2;
      #pragma unroll
      for (int d=1; d<64; d<<=1) sm += __shfl_xor(sm, d);
      float inv = 1.f / sm;
      attp[PADI(tid)]     = e0 * inv;
      attp[PADI(tid+64)]  = e1 * inv;
      attp[PADI(tid+128)] = e2 * inv;
    }
    __syncthreads();

    // ===== ctx partials (all blocks) =====
    {
      float pc0=0,pc1=0,pc2=0,pc3=0,pc4=0,pc5=0,pc6=0,pc7=0;
      #pragma unroll
      for (int j = 0; j < 12; ++j){
        float pj = attp[PADI(rs*12 + j)];
        uint4 v = vals_r[j];
        pc0 = fmaf(__uint_as_float(v.x << 16),         pj, pc0);
        pc1 = fmaf(__uint_as_float(v.x & 0xffff0000u), pj, pc1);
        pc2 = fmaf(__uint_as_float(v.y << 16),         pj, pc2);
        pc3 = fmaf(__uint_as_float(v.y & 0xffff0000u), pj, pc3);
        pc4 = fmaf(__uint_as_float(v.z << 16),         pj, pc4);
        pc5 = fmaf(__uint_as_float(v.z & 0xffff0000u), pj, pc5);
        pc6 = fmaf(__uint_as_float(v.w << 16),         pj, pc6);
        pc7 = fmaf(__uint_as_float(v.w & 0xffff0000u), pj, pc7);
      }
      *(float4*)&scratch[tid*8]   = make_float4(pc0,pc1,pc2,pc3);
      *(float4*)&scratch[tid*8+4] = make_float4(pc4,pc5,pc6,pc7);
    }
    __syncthreads();
    if (tid < 128){
      float s = 0.f;
      #pragma unroll
      for (int sg = 0; sg < 16; ++sg) s += scratch[sg*128 + tid];
      ctxS[PADI(tid)] = s;
    }
    __syncthreads();

    // ===== LSTM1 tail: ctx chunk + gates =====
    {
      acc1 += dot8(w1row[256 + ks], ctxS + ko);
      acc1 += __shfl_xor(acc1,1); acc1 += __shfl_xor(acc1,2);
      acc1 += __shfl_xor(acc1,4); acc1 += __shfl_xor(acc1,8);
      if (ks == 0) zred[rs] = acc1 + b1s[rs];
    }
    __syncthreads();
    if (tid < 4) {
      float zi=zred[tid], zf=zred[4+tid], zg=zred[8+tid], zo=zred[12+tid];
      float c = sigf(zf)*cst[1][tid] + sigf(zi)*tanhf_(zg);
      float h = sigf(zo)*tanhf_(c);
      cst[1][tid] = c;
      astx(h1buf + bid*4 + tid, tagf(h, TAG));
    }

    // ---- hop shadow: next step's Whh_att @ ha(t) ----
    {
      float a = 0.f;
      #pragma unroll
      for (int j = 1; j < 9; ++j) a += dot8(wa[j], haPrevS + (j-1)*144 + ko);
      accA = a;
    }

    // ---- poll h1 -> S2 ----
    poll4(h1buf, S2, TAG);
    __syncthreads();

    // ===== LSTM2 tail =====
    {
      #pragma unroll
      for (int j = 0; j < 8; ++j) acc2 += dot8(w2row[j*16 + ks], S2 + j*144 + ko);
      acc2 += __shfl_xor(acc2,1); acc2 += __shfl_xor(acc2,2);
      acc2 += __shfl_xor(acc2,4); acc2 += __shfl_xor(acc2,8);
      if (ks == 0) zred[rs] = acc2 + b2s[rs];
    }
    __syncthreads();
    if (tid < 4) {
      float zi=zred[tid], zf=zred[4+tid], zg=zred[8+tid], zo=zred[12+tid];
      float c = sigf(zf)*cst[2][tid] + sigf(zi)*tanhf_(zg);
      float h = sigf(zo)*tanhf_(c);
      cst[2][tid] = c;
      astx(h2buf + bid*4 + tid, tagf(h, TAG));
    }

    // ---- poll h2 -> S3 ----
    poll4(h2buf, S3, TAG);
    __syncthreads();
    // preload x-row for this col (consumed by next step's A-tail + out blocks)
    if (tid < 80) xrow[tid] = xsrc[col*80 + tid];

    // ===== hd = tanh(h2@Wd + bd); store tagged slice =====
    {
      int k6 = tid & 63, r2 = tid >> 6;
      int kk = k6*8 + ((k6>>2)<<2);
      float acc = dot8(wd[0], S3 + kk) + dot8(wd[1], S3 + 576 + kk);
      #pragma unroll
      for (int d=1; d<64; d<<=1) acc += __shfl_xor(acc, d);
      if (k6 == 0) astx(hdbuf + bid*4 + r2, tagf(tanhf_(acc + bds[r2]), TAG));
    }

    // ===== out blocks: publish (bp, ls); write ydst =====
    if (bid < 80) {
      poll4(hdbuf, scratch, TAG);
      __syncthreads();
      int po = tid*4 + ((tid>>3)<<2);
      float pb = dot4(wo0, scratch + po);
      float pl = dot4(wo1, scratch + po);
      #pragma unroll
      for (int d=1; d<64; d<<=1) { pb += __shfl_xor(pb, d); pl += __shfl_xor(pl, d); }
      if ((tid & 63) == 0) { zred[16+wid] = pb; zred[20+wid] = pl; }
      __syncthreads();
      if (tid == 0) {
        float bp = tagf(zred[16]+zred[17]+zred[18]+zred[19] + bos[0], TAG);
        float ls = tagf(zred[20]+zred[21]+zred[22]+zred[23] + bos[1], TAG);
        astx(bpl + bid, bp);
        astx(bpl + 80 + bid, ls);
        float y = (xrow[bid] - bp) * __expf(-ls);   // exact value consumers reconstruct
        if (out_mode == 0) ydst[col*80 + bid] = y;
        else               ydst[bid*512 + col] = y;
      }
    }

    // ---- poll (bp,ls) -> bplS (all blocks); next A-tail reconstructs y ----
    poll1(bpl, 160, bplS, TAG);
    __syncthreads();
  }
}

// ---------------- launch ----------------
extern "C" void kernel_launch(void* const* d_in, const int* in_sizes, int n_in,
                              void* d_out, int out_size, void* d_ws, size_t ws_size,
                              hipStream_t stream) {
  if (ws_size < NEEDED) return;
  uint8_t* ws = (uint8_t*)d_ws;
  const float* residual = (const float*)d_in[0];
  const float* spk      = (const float*)d_in[1];
  const float* emb      = (const float*)d_in[2];
  const float* Wih_att  = (const float*)d_in[3];
  const float* Whh_att  = (const float*)d_in[4];
  const float* b_att    = (const float*)d_in[5];
  const float* Wq       = (const float*)d_in[6];
  const float* Wk       = (const float*)d_in[7];
  const float* Wv       = (const float*)d_in[8];
  const float* Wih1     = (const float*)d_in[9];
  const float* Whh1     = (const float*)d_in[10];
  const float* b1       = (const float*)d_in[11];
  const float* Wih2     = (const float*)d_in[12];
  const float* Whh2     = (const float*)d_in[13];
  const float* b2       = (const float*)d_in[14];
  const float* Wd       = (const float*)d_in[15];
  const float* bd       = (const float*)d_in[16];
  const float* Wo       = (const float*)d_in[17];
  const float* bo       = (const float*)d_in[18];
  const int*   text     = (const int*)d_in[21];

  dim3 B(256);
  k_rbuf<<<160, B, 0, stream>>>(residual, (float*)(ws+OFF_RB));
  k_enc<<<480, B, 0, stream>>>(emb, spk, text, (float*)(ws+OFF_ENC));
  k_keysvals<<<192, B, 0, stream>>>((const float*)(ws+OFF_ENC), Wk, Wv,
                                    (float*)(ws+OFF_KEY), (float*)(ws+OFF_V32));
  k_wqT<<<1024, B, 0, stream>>>(Wq, (float*)(ws+OFF_WQT));
  k_wqk2<<<384, B, 0, stream>>>((const float*)(ws+OFF_WQT), (const float*)(ws+OFF_KEY),
                                (uint2*)(ws+OFF_WQ));
  k_packV2<<<24, B, 0, stream>>>((const float*)(ws+OFF_V32), (uint4*)(ws+OFF_VL));
  k_packA2<<<4608, B, 0, stream>>>(Wih_att, Whh_att, (uint4*)(ws+OFF_WA));
  k_pack1b<<<8736, B, 0, stream>>>(Wih1, Whh1, (uint4*)(ws+OFF_W1));
  k_pack2b<<<8224, B, 0, stream>>>(Wih2, Whh2, (uint4*)(ws+OFF_W2));
  k_packD2<<<512, B, 0, stream>>>(Wd, (uint4*)(ws+OFF_WD));
  k_packO2<<<160, B, 0, stream>>>(Wo, (uint2*)(ws+OFF_WO));

  // flow 1 (backward): rb -> seq
  k_init<<<20, B, 0, stream>>>((float*)(ws+OFF_DYN), (int)(DYN_BYTES/4));
  k_flow9<<<256, B, 0, stream>>>(ws, 1, 1, 0, b_att, b1, b2, bd, bo,
                                 (const float*)(ws+OFF_RB), (float*)(ws+OFF_SEQ));
  // flow 0 (forward): seq -> dout
  k_init<<<20, B, 0, stream>>>((float*)(ws+OFF_DYN), (int)(DYN_BYTES/4));
  k_flow9<<<256, B, 0, stream>>>(ws, 0, 0, 1, b_att, b1, b2, bd, bo,
                                 (const float*)(ws+OFF_SEQ), (float*)d_out);
}

// Round 10
// 23391.182 us; speedup vs baseline: 1.1914x; 1.1914x over previous
//
#include <hip/hip_runtime.h>
#include <hip/hip_bf16.h>
#include <stdint.h>

#define AG __HIP_MEMORY_SCOPE_AGENT
typedef unsigned long long ull;

// ---------------- workspace layout (bytes) ----------------
static constexpr size_t OFF_WA  = 0;                 // [2][256][256][9] uint4 (att-LSTM regs; j0=y-chunk, j1..8=haPrev)
static constexpr size_t OFF_W1  = 18874368;          // [2][256][16][2184] bf16 (LDS image, K=2176+pad)
static constexpr size_t OFF_W2  = 54657024;          // [2][256][16][2056] bf16 (LDS image, K=2048+pad)
static constexpr size_t OFF_WD  = 88342528;          // [2][256][256][2] uint4 (Wd regs)
static constexpr size_t OFF_WO  = 92536832;          // [2][80][256][2] uint2 (Wo regs)
static constexpr size_t OFF_WQ  = 93192192;          // [2][192][256] uint2 (Wq@keys^T * inv)
static constexpr size_t OFF_VL  = 93978624;          // [2][192][16] uint4 (vals: s-major, 8 a per uint4)
static constexpr size_t OFF_KEY = 94109696;          // [2][192][128] f32
static constexpr size_t OFF_V32 = 94306304;          // [2][192][128] f32 vals
static constexpr size_t OFF_WQT = 94502912;          // [2][128][1024] f32 Wq^T
static constexpr size_t OFF_ENC = 95551488;          // [192][640] f32
static constexpr size_t OFF_RB  = 96043008;          // residual^T [512][80] f32
static constexpr size_t OFF_SEQ = 96206848;          // intermediate seq [512][80] f32
static constexpr size_t OFF_DYN = 96370688;
static constexpr size_t OFF_HAb = OFF_DYN + 0;       // ha [1024] f32
static constexpr size_t OFF_H1b = OFF_DYN + 4096;    // h1 [1024]
static constexpr size_t OFF_H2b = OFF_DYN + 8192;    // h2 [1024]
static constexpr size_t OFF_HDb = OFF_DYN + 12288;   // hd [1024]
static constexpr size_t OFF_YBb = OFF_DYN + 16384;   // y [96 used, 128 alloc]
static constexpr size_t OFF_SCb = OFF_DYN + 16896;   // scores [192]
static constexpr size_t OFF_CXb = OFF_DYN + 17920;   // (unused)
static constexpr size_t OFF_FLG = OFF_DYN + 18432;   // flags [6][256][32] int (mode0) / counters [6][32][32] (mode1)
static constexpr size_t DYN_BYTES = 18432 + 229376;
static constexpr size_t NEEDED = OFF_DYN + DYN_BYTES;

// phase indices
#define PA 0
#define PS 1
#define P1 2
#define P2 3
#define PD 4
#define PF 5

// ---------------- device helpers ----------------
__device__ __forceinline__ float aldx(const float* p){ return __hip_atomic_load(p, __ATOMIC_RELAXED, AG); }
__device__ __forceinline__ void  astx(float* p, float v){ __hip_atomic_store(p, v, __ATOMIC_RELAXED, AG); }
__device__ __forceinline__ ull   aldx8(const ull* p){ return __hip_atomic_load(p, __ATOMIC_RELAXED, AG); }
__device__ __forceinline__ int   ldi(const int* p){ return __hip_atomic_load(p, __ATOMIC_RELAXED, AG); }
__device__ __forceinline__ int   PADI(int k){ return k + ((k>>5)<<2); }   // +16B per 32 floats

__device__ __forceinline__ float dot8(uint4 w, const float* v){
  float4 a = *(const float4*)v;
  float4 b = *(const float4*)(v+4);
  float s;
  s = __uint_as_float(w.x << 16) * a.x;
  s = fmaf(__uint_as_float(w.x & 0xffff0000u), a.y, s);
  s = fmaf(__uint_as_float(w.y << 16),         a.z, s);
  s = fmaf(__uint_as_float(w.y & 0xffff0000u), a.w, s);
  s = fmaf(__uint_as_float(w.z << 16),         b.x, s);
  s = fmaf(__uint_as_float(w.z & 0xffff0000u), b.y, s);
  s = fmaf(__uint_as_float(w.w << 16),         b.z, s);
  s = fmaf(__uint_as_float(w.w & 0xffff0000u), b.w, s);
  return s;
}
__device__ __forceinline__ float dot4(uint2 w, const float* v){
  float4 a = *(const float4*)v;
  float s;
  s = __uint_as_float(w.x << 16) * a.x;
  s = fmaf(__uint_as_float(w.x & 0xffff0000u), a.y, s);
  s = fmaf(__uint_as_float(w.y << 16),         a.z, s);
  s = fmaf(__uint_as_float(w.y & 0xffff0000u), a.w, s);
  return s;
}
__device__ __forceinline__ float sigf(float x){ return 1.f/(1.f+__expf(-x)); }
__device__ __forceinline__ float tanhf_(float x){
  x = fminf(12.f, fmaxf(-12.f, x));
  float t = __expf(2.f*x);
  return (t-1.f)/(t+1.f);
}

// ---------------- prep kernels ----------------
__global__ void k_init(float* z, int n){ int i = blockIdx.x*256 + threadIdx.x; if (i<n) z[i]=0.f; }

__global__ void k_rbuf(const float* res, float* rb){
  int i = blockIdx.x*256 + threadIdx.x; if (i >= 512*80) return;
  int t = i/80, m = i - t*80;
  rb[i] = res[m*512 + t];
}

__global__ void k_enc(const float* emb, const float* spk, const int* text, float* enc){
  int i = blockIdx.x*256 + threadIdx.x; if (i >= 192*640) return;
  int s = i/640, e = i - s*640;
  enc[i] = (e < 512) ? emb[(size_t)text[s]*512 + e] : spk[e-512];
}

__global__ void k_keysvals(const float* enc, const float* Wk, const float* Wv,
                           float* keys, float* vals32){
  int i = blockIdx.x*256 + threadIdx.x; if (i >= 2*192*128) return;
  int f = i/(192*128); int r = i - f*192*128; int s = r/128, a = r - s*128;
  float ka=0.f, va=0.f;
  for (int e=0;e<640;++e){
    float x = enc[s*640+e];
    ka = fmaf(x, Wk[((size_t)f*640+e)*128+a], ka);
    va = fmaf(x, Wv[((size_t)f*640+e)*128+a], va);
  }
  keys[((size_t)f*192+s)*128+a] = ka;
  vals32[((size_t)f*192+s)*128+a] = va;
}

__global__ void k_wqT(const float* Wq, float* WqT){
  int i = blockIdx.x*256 + threadIdx.x; if (i >= 2*128*1024) return;
  int f = i/(128*1024); int r = i - f*128*1024; int a = r/1024, h = r - a*1024;
  WqT[i] = Wq[((size_t)f*1024+h)*128+a];
}

__global__ void k_wqk2(const float* WqT, const float* keys, uint2* dst){
  int b = blockIdx.x; int f = b/192, s = b - f*192;
  int t = threadIdx.x;
  float4 acc = {0.f,0.f,0.f,0.f};
  const float* kp = keys + ((size_t)f*192+s)*128;
  const float* wp = WqT + (size_t)f*128*1024 + t*4;
  for (int a=0;a<128;++a){
    float kk = kp[a];
    float4 w = *(const float4*)(wp + (size_t)a*1024);
    acc.x = fmaf(kk, w.x, acc.x); acc.y = fmaf(kk, w.y, acc.y);
    acc.z = fmaf(kk, w.z, acc.z); acc.w = fmaf(kk, w.w, acc.w);
  }
  const float inv = 0.08838834764831845f;
  __hip_bfloat16 b0 = __float2bfloat16(acc.x*inv), b1 = __float2bfloat16(acc.y*inv);
  __hip_bfloat16 b2 = __float2bfloat16(acc.z*inv), b3 = __float2bfloat16(acc.w*inv);
  uint2 o;
  o.x = (uint32_t)(*(uint16_t*)&b0) | ((uint32_t)(*(uint16_t*)&b1) << 16);
  o.y = (uint32_t)(*(uint16_t*)&b2) | ((uint32_t)(*(uint16_t*)&b3) << 16);
  dst[((size_t)f*192+s)*256 + t] = o;
}

__device__ __forceinline__ uint32_t pk2(float a, float b){
  __hip_bfloat16 x = __float2bfloat16(a), y = __float2bfloat16(b);
  return (uint32_t)(*(uint16_t*)&x) | ((uint32_t)(*(uint16_t*)&y) << 16);
}

// vals packed s-major: dst[(f*192+s)*16 + ag] = 8 bf16 (a = ag*8..+8)
__global__ void k_packV2(const float* vals32, uint4* dst){
  int i = blockIdx.x*256 + threadIdx.x; if (i >= 2*192*16) return;
  int ag = i & 15; int r = i >> 4;
  int s = r % 192; int f = r / 192;
  float v[8];
  for (int e=0;e<8;++e) v[e] = vals32[((size_t)f*192+s)*128 + ag*8 + e];
  uint4 o; o.x = pk2(v[0],v[1]); o.y = pk2(v[2],v[3]); o.z = pk2(v[4],v[5]); o.w = pk2(v[6],v[7]);
  dst[i] = o;
}

__global__ void k_packA2(const float* Wih, const float* Whh, uint4* dst){
  int i = blockIdx.x*256 + threadIdx.x; if (i >= 2*256*256*9) return;
  int j = i % 9; int r = i / 9;
  int t = r & 255; r >>= 8;
  int b = r & 255; int f = r >> 8;
  int rs = t>>4, ks = t&15;
  int row = (rs>>2)*1024 + b*4 + (rs&3);
  float v[8];
  for (int e=0;e<8;++e){
    int c = ks*8 + e;
    if (j == 0) v[e] = (c < 80) ? Wih[((size_t)f*4096+row)*80 + c] : 0.f;
    else        v[e] = Whh[((size_t)f*4096+row)*1024 + (j-1)*128 + c];
  }
  uint4 o; o.x = pk2(v[0],v[1]); o.y = pk2(v[2],v[3]); o.z = pk2(v[4],v[5]); o.w = pk2(v[6],v[7]);
  dst[i] = o;
}

__global__ void k_pack1b(const float* Wih1, const float* Whh1, uint4* dst){
  int i = blockIdx.x*256 + threadIdx.x; if (i >= 2*256*16*273) return;
  int kc = i % 273; int r = i / 273;
  int rr = r & 15; r >>= 4;
  int b = r & 255; int f = r >> 8;
  int row = (rr>>2)*1024 + b*4 + (rr&3);
  int k0 = kc*8;
  float v[8];
  for (int e=0;e<8;++e){
    int k = k0+e; float x;
    if (k < 1024)      x = Wih1[((size_t)f*4096+row)*1152 + k];
    else if (k < 2048) x = Whh1[((size_t)f*4096+row)*1024 + (k-1024)];
    else if (k < 2176) x = Wih1[((size_t)f*4096+row)*1152 + 1024 + (k-2048)];
    else               x = 0.f;
    v[e] = x;
  }
  uint4 o; o.x = pk2(v[0],v[1]); o.y = pk2(v[2],v[3]); o.z = pk2(v[4],v[5]); o.w = pk2(v[6],v[7]);
  dst[i] = o;
}

__global__ void k_pack2b(const float* Wih2, const float* Whh2, uint4* dst){
  int i = blockIdx.x*256 + threadIdx.x; if (i >= 2*256*16*257) return;
  int kc = i % 257; int r = i / 257;
  int rr = r & 15; r >>= 4;
  int b = r & 255; int f = r >> 8;
  int row = (rr>>2)*1024 + b*4 + (rr&3);
  int k0 = kc*8;
  float v[8];
  for (int e=0;e<8;++e){
    int k = k0+e;
    v[e] = (k < 1024) ? Wih2[((size_t)f*4096+row)*1024 + k]
         : (k < 2048) ? Whh2[((size_t)f*4096+row)*1024 + (k-1024)] : 0.f;
  }
  uint4 o; o.x = pk2(v[0],v[1]); o.y = pk2(v[2],v[3]); o.z = pk2(v[4],v[5]); o.w = pk2(v[6],v[7]);
  dst[i] = o;
}

__global__ void k_packD2(const float* Wd, uint4* dst){
  __shared__ float tile[64][65];
  int b = blockIdx.x; int f = b >> 8; int rem = b & 255;
  int ot = rem >> 4, ct = rem & 15;
  int tid = threadIdx.x;
  for (int i = tid; i < 4096; i += 256){
    int rc = i >> 6, oc = i & 63;
    tile[rc][oc] = Wd[((size_t)f*1024 + ct*64 + rc)*1024 + ot*64 + oc];
  }
  __syncthreads();
  for (int w = 0; w < 2; ++w){
    int idx = w*256 + tid;
    int op = idx >> 3, cc = idx & 7;
    int k6 = (ct&7)*8 + cc, j = ct >> 3;
    int o = ot*64 + op;
    int b2 = o >> 2, r2 = o & 3;
    uint4 out;
    out.x = pk2(tile[cc*8+0][op], tile[cc*8+1][op]);
    out.y = pk2(tile[cc*8+2][op], tile[cc*8+3][op]);
    out.z = pk2(tile[cc*8+4][op], tile[cc*8+5][op]);
    out.w = pk2(tile[cc*8+6][op], tile[cc*8+7][op]);
    dst[((((size_t)f*256 + b2)*256) + r2*64 + k6)*2 + j] = out;
  }
}

__global__ void k_packO2(const float* Wo, uint2* dst){
  int i = blockIdx.x*256 + threadIdx.x; if (i >= 2*80*256) return;
  int t = i & 255; int r = i >> 8;
  int m = r % 80; int f = r / 80;
  for (int j = 0; j < 2; ++j){
    int row = m + j*80;
    float v[4];
    for (int e=0;e<4;++e) v[e] = Wo[((size_t)f*1024 + t*4+e)*160 + row];
    uint2 o; o.x = pk2(v[0],v[1]); o.y = pk2(v[2],v[3]);
    dst[(size_t)i*2 + j] = o;
  }
}

// ---------------- main persistent kernel (one flow) ----------------
__launch_bounds__(256, 1)
__global__ void k_flow5(uint8_t* ws, int fl, int rev, int out_mode, int smode,
    const float* b_att_all, const float* b1_all, const float* b2_all,
    const float* bd_all, const float* bo_all,
    const float* xsrc, float* ydst)
{
  const int tid = threadIdx.x, bid = blockIdx.x;
  const int rs = tid >> 4, ks = tid & 15;   // 16 rows x 16 k-slices (also sg/ag for ctx)
  const int wid = tid >> 6;
  const int ko = ks*8 + ((ks>>2)<<2);       // = PADI(ks*8)

  float* habuf = (float*)(ws + OFF_HAb);
  float* h1buf = (float*)(ws + OFF_H1b);
  float* h2buf = (float*)(ws + OFF_H2b);
  float* hdbuf = (float*)(ws + OFF_HDb);
  float* ybuf  = (float*)(ws + OFF_YBb);
  float* scb   = (float*)(ws + OFF_SCb);
  int*   flags = (int*)(ws + OFF_FLG);

  __shared__ __align__(16) ushort W1s[16*2184];
  __shared__ __align__(16) ushort W2s[16*2056];
  __shared__ __align__(16) float haPrevS[1152];
  __shared__ __align__(16) float S2[1152];      // h1prev / h1
  __shared__ __align__(16) float S3[1152];      // h2prev / h2
  __shared__ __align__(16) float scratch[2048]; // ctx partials (PS) / hd staging (PF)
  __shared__ __align__(16) float yS[144];
  __shared__ __align__(16) float ctxS[144];
  __shared__ __align__(16) float attp[288];
  __shared__ float zred[32];
  __shared__ float cst[3][4];
  __shared__ float bAs[16], b1s[16], b2s[16], bds[4], bos[2];

  const size_t fb = (size_t)fl*256 + bid;

  // ---- prologue: weights to LDS / regs ----
  { const uint4* src = (const uint4*)((const ushort*)(ws + OFF_W1) + fb*16*2184);
    uint4* dst = (uint4*)W1s;
    for (int i = tid; i < 4368; i += 256) dst[i] = src[i]; }
  { const uint4* src = (const uint4*)((const ushort*)(ws + OFF_W2) + fb*16*2056);
    uint4* dst = (uint4*)W2s;
    for (int i = tid; i < 4112; i += 256) dst[i] = src[i]; }
  uint4 wa[9];
  { const uint4* g = (const uint4*)(ws + OFF_WA) + (fb*256 + tid)*9;
    #pragma unroll
    for (int j = 0; j < 9; ++j) wa[j] = g[j]; }
  uint4 wd[2];
  { const uint4* g = (const uint4*)(ws + OFF_WD) + (fb*256 + tid)*2;
    wd[0] = g[0]; wd[1] = g[1]; }
  uint2 wqk = {0,0};
  if (bid < 192) wqk = ((const uint2*)(ws + OFF_WQ))[((size_t)fl*192 + bid)*256 + tid];
  uint4 vals_r[12];
  { const uint4* g = (const uint4*)(ws + OFF_VL) + (((size_t)fl*192 + rs*12)*16 + ks);
    #pragma unroll
    for (int j = 0; j < 12; ++j) vals_r[j] = g[(size_t)j*16]; }
  uint2 wo0 = {0,0}, wo1 = {0,0};
  if (bid < 80){ const uint2* g = (const uint2*)(ws + OFF_WO) + (((size_t)fl*80 + bid)*256 + tid)*2;
    wo0 = g[0]; wo1 = g[1]; }
  if (tid < 16){
    int g = tid >> 2, uu = tid & 3;
    bAs[tid] = b_att_all[fl*4096 + g*1024 + bid*4 + uu];
    b1s[tid] = b1_all  [fl*4096 + g*1024 + bid*4 + uu];
    b2s[tid] = b2_all  [fl*4096 + g*1024 + bid*4 + uu];
  }
  if (tid < 4)  bds[tid] = bd_all[fl*1024 + bid*4 + tid];
  if (tid < 2 && bid < 80) bos[tid] = bo_all[fl*160 + tid*80 + bid];
  if (tid < 12) ((float*)cst)[tid] = 0.f;
  for (int i = tid; i < 1152; i += 256){ haPrevS[i]=0.f; S2[i]=0.f; S3[i]=0.f; }
  if (tid < 144){ yS[tid]=0.f; ctxS[tid]=0.f; }
  __syncthreads();

  // RELAXED signal: __syncthreads() drains each thread's stores (vmcnt(0) before
  // s_barrier), so a subsequent relaxed agent-scope flag store is ordered after
  // all data stores at the coherence point. No release -> no L2 writeback walk.
  auto SIG = [&](int ph, int tp1){
    __syncthreads();
    __builtin_amdgcn_sched_barrier(0);
    if (tid == 0){
      if (smode == 0) __hip_atomic_store(flags + (ph*256 + bid)*32, tp1, __ATOMIC_RELAXED, AG);
      else            __hip_atomic_fetch_add(flags + (ph*32 + (bid>>3))*32, 1, __ATOMIC_RELAXED, AG);
    }
  };
  auto WAITF = [&](int ph, int base, int n, int tp1){
    if (smode == 0){
      if (tid < n){
        const int* f = flags + (ph*256 + base + tid)*32;
        while (ldi(f) < tp1) __builtin_amdgcn_s_sleep(1);
      }
    } else {
      int nl = n >> 3, bl = base >> 3, tgt = tp1*8;
      if (tid < nl){
        const int* f = flags + (ph*32 + bl + tid)*32;
        while (ldi(f) < tgt) __builtin_amdgcn_s_sleep(1);
      }
    }
    __syncthreads();
  };
  auto stage_pad = [&](const float* g, float* s){
    const ull* g8 = (const ull*)g;
    #pragma unroll
    for (int i = tid; i < 512; i += 256){
      ull v = aldx8(g8 + i);
      int k = i*2;
      *(ull*)&s[k + ((k>>5)<<2)] = v;
    }
  };

  const uint4* w1row = (const uint4*)(W1s) + (size_t)rs*273;
  const uint4* w2row = (const uint4*)(W2s) + (size_t)rs*257;

  float accA = 0.f;   // Whh_att @ haPrev, precomputed in the P1-hop shadow

  for (int t = 0; t < 512; ++t) {
    const int col = rev ? (511 - t) : t;
    const int tp1 = t + 1;
    float x = 0.f;
    if (bid < 80) x = xsrc[col*80 + bid];

    // ===== phase A tail: only the y-dependent chunk =====
    {
      float acc = accA + dot8(wa[0], yS + ko);
      acc += __shfl_xor(acc,1); acc += __shfl_xor(acc,2);
      acc += __shfl_xor(acc,4); acc += __shfl_xor(acc,8);
      if (ks == 0) zred[rs] = acc + bAs[rs];
    }
    __syncthreads();
    if (tid < 4) {
      float zi=zred[tid], zf=zred[4+tid], zg=zred[8+tid], zo=zred[12+tid];
      float c = sigf(zf)*cst[0][tid] + sigf(zi)*tanhf_(zg);
      float h = sigf(zo)*tanhf_(c);
      cst[0][tid] = c;
      astx(habuf + bid*4 + tid, h);
    }
    SIG(PA, tp1);

    // ---- PA-hop shadow: prev-state halves of LSTM1/LSTM2 ----
    float acc1 = 0.f, acc2 = 0.f;
    #pragma unroll
    for (int j = 0; j < 8; ++j) acc1 += dot8(w1row[(j+8)*16 + ks], S2 + j*144 + ko);
    #pragma unroll
    for (int j = 0; j < 8; ++j) acc2 += dot8(w2row[(j+8)*16 + ks], S3 + j*144 + ko);

    WAITF(PA, 0, 256, tp1);
    stage_pad(habuf, haPrevS);   // haPrevS = ha(t)
    __syncthreads();

    // ===== scores (blocks 0..191) =====
    if (bid < 192) {
      float sv = dot4(wqk, haPrevS + tid*4 + ((tid>>3)<<2));
      #pragma unroll
      for (int d=1; d<64; d<<=1) sv += __shfl_xor(sv, d);
      if ((tid&63) == 0) zred[16+wid] = sv;
      __syncthreads();
      if (tid == 0) astx(scb + bid, zred[16]+zred[17]+zred[18]+zred[19]);
      SIG(PS, tp1);
    }

    // ---- PS-hop shadow: LSTM1 ha-half ----
    #pragma unroll
    for (int j = 0; j < 8; ++j) acc1 += dot8(w1row[j*16 + ks], haPrevS + j*144 + ko);

    // ===== all blocks: local softmax + ctx =====
    WAITF(PS, 0, 192, tp1);
    if (tid < 96){ ull v = aldx8((const ull*)scb + tid); int k=tid*2;
                   *(ull*)&attp[k + ((k>>5)<<2)] = v; }
    __syncthreads();
    {
      float v = (tid < 192) ? attp[PADI(tid)] : -3.0e38f;
      float m = v;
      #pragma unroll
      for (int d=1; d<64; d<<=1) m = fmaxf(m, __shfl_xor(m, d));
      if ((tid&63) == 0) zred[16+wid] = m;
      __syncthreads();
      float mx = fmaxf(fmaxf(zred[16],zred[17]), fmaxf(zred[18],zred[19]));
      float e = (tid < 192) ? __expf(v - mx) : 0.f;
      float sm = e;
      #pragma unroll
      for (int d=1; d<64; d<<=1) sm += __shfl_xor(sm, d);
      if ((tid&63) == 0) zred[20+wid] = sm;
      __syncthreads();
      float inv = 1.f / (zred[20]+zred[21]+zred[22]+zred[23]);
      attp[PADI(tid)] = (tid < 192) ? e * inv : 0.f;
    }
    __syncthreads();
    {
      // ctx partial: thread (sg=rs, ag=ks) covers s in [rs*12, rs*12+12), a in [ks*8, ks*8+8)
      float pc0=0,pc1=0,pc2=0,pc3=0,pc4=0,pc5=0,pc6=0,pc7=0;
      #pragma unroll
      for (int j = 0; j < 12; ++j){
        float pj = attp[PADI(rs*12 + j)];
        uint4 v = vals_r[j];
        pc0 = fmaf(__uint_as_float(v.x << 16),         pj, pc0);
        pc1 = fmaf(__uint_as_float(v.x & 0xffff0000u), pj, pc1);
        pc2 = fmaf(__uint_as_float(v.y << 16),         pj, pc2);
        pc3 = fmaf(__uint_as_float(v.y & 0xffff0000u), pj, pc3);
        pc4 = fmaf(__uint_as_float(v.z << 16),         pj, pc4);
        pc5 = fmaf(__uint_as_float(v.z & 0xffff0000u), pj, pc5);
        pc6 = fmaf(__uint_as_float(v.w << 16),         pj, pc6);
        pc7 = fmaf(__uint_as_float(v.w & 0xffff0000u), pj, pc7);
      }
      *(float4*)&scratch[tid*8]   = make_float4(pc0,pc1,pc2,pc3);
      *(float4*)&scratch[tid*8+4] = make_float4(pc4,pc5,pc6,pc7);
    }
    __syncthreads();
    if (tid < 128){
      float s = 0.f;
      #pragma unroll
      for (int sg = 0; sg < 16; ++sg) s += scratch[sg*128 + tid];
      ctxS[PADI(tid)] = s;
    }
    __syncthreads();

    // ===== LSTM1 tail: ctx chunk + gates =====
    {
      acc1 += dot8(w1row[256 + ks], ctxS + ko);
      acc1 += __shfl_xor(acc1,1); acc1 += __shfl_xor(acc1,2);
      acc1 += __shfl_xor(acc1,4); acc1 += __shfl_xor(acc1,8);
      if (ks == 0) zred[rs] = acc1 + b1s[rs];
    }
    __syncthreads();
    if (tid < 4) {
      float zi=zred[tid], zf=zred[4+tid], zg=zred[8+tid], zo=zred[12+tid];
      float c = sigf(zf)*cst[1][tid] + sigf(zi)*tanhf_(zg);
      float h = sigf(zo)*tanhf_(c);
      cst[1][tid] = c;
      astx(h1buf + bid*4 + tid, h);
    }
    SIG(P1, tp1);

    // ---- P1-hop shadow: next step's Whh_att @ ha(t) ----
    {
      float a = 0.f;
      #pragma unroll
      for (int j = 1; j < 9; ++j) a += dot8(wa[j], haPrevS + (j-1)*144 + ko);
      accA = a;
    }

    WAITF(P1, 0, 256, tp1);
    stage_pad(h1buf, S2);   // S2 = h1(t)
    __syncthreads();

    // ===== LSTM2 tail =====
    {
      #pragma unroll
      for (int j = 0; j < 8; ++j) acc2 += dot8(w2row[j*16 + ks], S2 + j*144 + ko);
      acc2 += __shfl_xor(acc2,1); acc2 += __shfl_xor(acc2,2);
      acc2 += __shfl_xor(acc2,4); acc2 += __shfl_xor(acc2,8);
      if (ks == 0) zred[rs] = acc2 + b2s[rs];
    }
    __syncthreads();
    if (tid < 4) {
      float zi=zred[tid], zf=zred[4+tid], zg=zred[8+tid], zo=zred[12+tid];
      float c = sigf(zf)*cst[2][tid] + sigf(zi)*tanhf_(zg);
      float h = sigf(zo)*tanhf_(c);
      cst[2][tid] = c;
      astx(h2buf + bid*4 + tid, h);
    }
    SIG(P2, tp1);
    WAITF(P2, 0, 256, tp1);
    stage_pad(h2buf, S3);   // S3 = h2(t)
    __syncthreads();

    // ===== hd = tanh(h2@Wd + bd) =====
    {
      int k6 = tid & 63, r2 = tid >> 6;
      int kk = k6*8 + ((k6>>2)<<2);
      float acc = dot8(wd[0], S3 + kk) + dot8(wd[1], S3 + 576 + kk);
      #pragma unroll
      for (int d=1; d<64; d<<=1) acc += __shfl_xor(acc, d);
      if (k6 == 0) astx(hdbuf + bid*4 + r2, tanhf_(acc + bds[r2]));
    }
    SIG(PD, tp1);

    // ===== out blocks: y = (x - bp)*exp(-ls) =====
    if (bid < 80) {
      WAITF(PD, 0, 256, tp1);
      stage_pad(hdbuf, scratch);
      __syncthreads();
      int po = tid*4 + ((tid>>3)<<2);
      float pb = dot4(wo0, scratch + po);
      float pl = dot4(wo1, scratch + po);
      #pragma unroll
      for (int d=1; d<64; d<<=1) { pb += __shfl_xor(pb, d); pl += __shfl_xor(pl, d); }
      if ((tid & 63) == 0) { zred[16+wid] = pb; zred[20+wid] = pl; }
      __syncthreads();
      if (tid == 0) {
        float bp = zred[16]+zred[17]+zred[18]+zred[19] + bos[0];
        float ls = zred[20]+zred[21]+zred[22]+zred[23] + bos[1];
        float y = (x - bp) * __expf(-ls);
        if (out_mode == 0) ydst[col*80 + bid] = y;
        else               ydst[bid*512 + col] = y;
        astx(ybuf + bid, y);
      }
      SIG(PF, tp1);
    }
    WAITF(PF, 0, 80, tp1);
    if (tid < 64){ ull v = (tid < 40) ? aldx8((const ull*)ybuf + tid) : 0ull;
                   int k = tid*2; *(ull*)&yS[k + ((k>>5)<<2)] = v; }
    __syncthreads();
  }
}

// ---------------- launch ----------------
extern "C" void kernel_launch(void* const* d_in, const int* in_sizes, int n_in,
                              void* d_out, int out_size, void* d_ws, size_t ws_size,
                              hipStream_t stream) {
  if (ws_size < NEEDED) return;
  uint8_t* ws = (uint8_t*)d_ws;
  const float* residual = (const float*)d_in[0];
  const float* spk      = (const float*)d_in[1];
  const float* emb      = (const float*)d_in[2];
  const float* Wih_att  = (const float*)d_in[3];
  const float* Whh_att  = (const float*)d_in[4];
  const float* b_att    = (const float*)d_in[5];
  const float* Wq       = (const float*)d_in[6];
  const float* Wk       = (const float*)d_in[7];
  const float* Wv       = (const float*)d_in[8];
  const float* Wih1     = (const float*)d_in[9];
  const float* Whh1     = (const float*)d_in[10];
  const float* b1       = (const float*)d_in[11];
  const float* Wih2     = (const float*)d_in[12];
  const float* Whh2     = (const float*)d_in[13];
  const float* b2       = (const float*)d_in[14];
  const float* Wd       = (const float*)d_in[15];
  const float* bd       = (const float*)d_in[16];
  const float* Wo       = (const float*)d_in[17];
  const float* bo       = (const float*)d_in[18];
  const int*   text     = (const int*)d_in[21];

  dim3 B(256);
  k_rbuf<<<160, B, 0, stream>>>(residual, (float*)(ws+OFF_RB));
  k_enc<<<480, B, 0, stream>>>(emb, spk, text, (float*)(ws+OFF_ENC));
  k_keysvals<<<192, B, 0, stream>>>((const float*)(ws+OFF_ENC), Wk, Wv,
                                    (float*)(ws+OFF_KEY), (float*)(ws+OFF_V32));
  k_wqT<<<1024, B, 0, stream>>>(Wq, (float*)(ws+OFF_WQT));
  k_wqk2<<<384, B, 0, stream>>>((const float*)(ws+OFF_WQT), (const float*)(ws+OFF_KEY),
                                (uint2*)(ws+OFF_WQ));
  k_packV2<<<24, B, 0, stream>>>((const float*)(ws+OFF_V32), (uint4*)(ws+OFF_VL));
  k_packA2<<<4608, B, 0, stream>>>(Wih_att, Whh_att, (uint4*)(ws+OFF_WA));
  k_pack1b<<<8736, B, 0, stream>>>(Wih1, Whh1, (uint4*)(ws+OFF_W1));
  k_pack2b<<<8224, B, 0, stream>>>(Wih2, Whh2, (uint4*)(ws+OFF_W2));
  k_packD2<<<512, B, 0, stream>>>(Wd, (uint4*)(ws+OFF_WD));
  k_packO2<<<160, B, 0, stream>>>(Wo, (uint2*)(ws+OFF_WO));

  // flow 1 (backward): rb -> seq   [sync mode A: per-block flag lines]
  k_init<<<242, B, 0, stream>>>((float*)(ws+OFF_DYN), (int)(DYN_BYTES/4));
  k_flow5<<<256, B, 0, stream>>>(ws, 1, 1, 0, 0, b_att, b1, b2, bd, bo,
                                 (const float*)(ws+OFF_RB), (float*)(ws+OFF_SEQ));
  // flow 0 (forward): seq -> dout  [sync mode B: 32-line counters]
  k_init<<<242, B, 0, stream>>>((float*)(ws+OFF_DYN), (int)(DYN_BYTES/4));
  k_flow5<<<256, B, 0, stream>>>(ws, 0, 0, 1, 1, b_att, b1, b2, bd, bo,
                                 (const float*)(ws+OFF_SEQ), (float*)d_out);
}